// Round 4
// baseline (704.485 us; speedup 1.0000x reference)
//
#include <hip/hip_runtime.h>
#include <math.h>

// RelationalMemoryCell: B=2048, S=8, H=8, M=1024, QKV=384, TOTAL=3072,
// IN_DIM=1024. fp32 in/out; GEMMs bf16 MFMA (fp32 accumulate).
//
// Pruning: m2[:, :-1] drops the s=8 row => MLP + attention q only for s=0..7.
// Gates (ig/fg) depend only on memory & x => precomputed, and the final
// blend out = ig*tanh(m2) + fg*mem is fused into the mlp1 GEMM epilogue.

typedef unsigned short ushort_t;                                  // bf16 bits
typedef short bf16x8_t __attribute__((ext_vector_type(8)));       // MFMA A/B frag
typedef float f32x4_t  __attribute__((ext_vector_type(4)));       // MFMA C/D frag

__device__ __forceinline__ ushort_t f2bf(float f) {               // RNE
    unsigned int u = __float_as_uint(f);
    u += 0x7fff + ((u >> 16) & 1);
    return (ushort_t)(u >> 16);
}
__device__ __forceinline__ float bf2f(ushort_t h) {
    return __uint_as_float(((unsigned int)h) << 16);
}
__device__ __forceinline__ float fast_tanh(float x) {             // sat-safe
    float e = __expf(2.0f * x);                                   // inf ok
    return 1.0f - 2.0f * __builtin_amdgcn_rcpf(e + 1.0f);
}
__device__ __forceinline__ float fast_sigmoid(float x) {
    return __builtin_amdgcn_rcpf(1.0f + __expf(-x));
}

__device__ __forceinline__ void load_lds_16(const void* g, void* l) {
    __builtin_amdgcn_global_load_lds(
        (const __attribute__((address_space(1))) void*)g,
        (__attribute__((address_space(3))) void*)l, 16, 0, 0);
}

// ---------------------------------------------------------------------------
// bf16 MFMA GEMM, 128x128 tile, BK=32, 4 waves, 4x4 x mfma_16x16x32_bf16.
// A: MxK bf16 row-major. Wt: NxK bf16 (pre-transposed W). XOR-swizzled LDS.
// Epilogue modes (by pointer nullness):
//   outp != 0 : out[row*N+col] = ig*tanh(v) + fg*mem  (v = acc+bias+res)
//   Cb   != 0 : bf16 store (opt res/relu)
//   else      : fp32 store into Cf
// ---------------------------------------------------------------------------
__global__ __launch_bounds__(256)
void gemm_mfma(const ushort_t* __restrict__ A, const ushort_t* __restrict__ Wt,
               const float* __restrict__ bias, float* __restrict__ Cf,
               ushort_t* __restrict__ Cb, const ushort_t* __restrict__ resb,
               const float* __restrict__ igfg, const float* __restrict__ memf,
               float* __restrict__ outp, int M, int N, int K, int relu)
{
    __shared__ __align__(16) ushort_t As[128 * 32];
    __shared__ __align__(16) ushort_t Bs[128 * 32];
    const int tid  = threadIdx.x;
    const int wave = tid >> 6, lane = tid & 63;
    const int wr = (wave >> 1) * 64;
    const int wc = (wave & 1)  * 64;
    const int lrow  = lane & 15;
    const int lquad = lane >> 4;
    const int rowBase = blockIdx.y * 128;
    const int colBase = blockIdx.x * 128;

    f32x4_t acc[4][4] = {};

    for (int k0 = 0; k0 < K; k0 += 32) {
        #pragma unroll
        for (int i = 0; i < 2; ++i) {
            int e    = i * 256 + tid;
            int row  = e >> 2;
            int c    = (e & 3) ^ ((row >> 1) & 3);
            const ushort_t* ga = A  + (size_t)(rowBase + row) * K + k0 + c * 8;
            const ushort_t* gb = Wt + (size_t)(colBase + row) * K + k0 + c * 8;
            load_lds_16(ga, &As[e * 8]);
            load_lds_16(gb, &Bs[e * 8]);
        }
        __syncthreads();

        bf16x8_t af[4], bfr[4];
        #pragma unroll
        for (int t = 0; t < 4; ++t) {
            int ma = wr + t * 16 + lrow;
            int pa = lquad ^ ((ma >> 1) & 3);
            af[t]  = *(const bf16x8_t*)&As[ma * 32 + pa * 8];
            int nb = wc + t * 16 + lrow;
            int pb = lquad ^ ((nb >> 1) & 3);
            bfr[t] = *(const bf16x8_t*)&Bs[nb * 32 + pb * 8];
        }
        #pragma unroll
        for (int mi = 0; mi < 4; ++mi)
            #pragma unroll
            for (int ni = 0; ni < 4; ++ni)
                acc[mi][ni] = __builtin_amdgcn_mfma_f32_16x16x32_bf16(
                    af[mi], bfr[ni], acc[mi][ni], 0, 0, 0);
        __syncthreads();
    }

    // D layout: col = lane&15, row = lquad*4 + r   [m89/m91]
    #pragma unroll
    for (int mi = 0; mi < 4; ++mi) {
        #pragma unroll
        for (int ni = 0; ni < 4; ++ni) {
            int col = colBase + wc + ni * 16 + lrow;
            float bv = bias[col];
            #pragma unroll
            for (int r = 0; r < 4; ++r) {
                int row = rowBase + wr + mi * 16 + lquad * 4 + r;
                size_t idx = (size_t)row * N + col;
                float v = acc[mi][ni][r] + bv;
                if (resb) v += bf2f(resb[idx]);
                if (relu) v = fmaxf(v, 0.f);
                if (outp) {
                    float ig = igfg[row * 2], fg = igfg[row * 2 + 1];
                    outp[idx] = ig * fast_tanh(v) + fg * memf[idx];
                } else if (Cb) {
                    Cb[idx] = f2bf(v);
                } else {
                    Cf[idx] = v;
                }
            }
        }
    }
}

// ---------------------------------------------------------------------------
// fp32 -> bf16 elementwise
// ---------------------------------------------------------------------------
__global__ __launch_bounds__(256)
void conv_bf16(const float* __restrict__ in, ushort_t* __restrict__ out, size_t n)
{
    size_t i = ((size_t)blockIdx.x * 256 + threadIdx.x) * 4;
    if (i >= n) return;
    float4 v = *(const float4*)(in + i);
    out[i + 0] = f2bf(v.x); out[i + 1] = f2bf(v.y);
    out[i + 2] = f2bf(v.z); out[i + 3] = f2bf(v.w);
}

// ---------------------------------------------------------------------------
// Weight transpose+convert: Wt[n][k] = bf16(W[k][n])
// ---------------------------------------------------------------------------
__global__ __launch_bounds__(256)
void conv_wt(const float* __restrict__ W, ushort_t* __restrict__ Wt, int K, int N)
{
    __shared__ float t[32][33];
    const int n0 = blockIdx.x * 32, k0 = blockIdx.y * 32;
    const int tx = threadIdx.x, ty = threadIdx.y;   // (32, 8)
    #pragma unroll
    for (int i = 0; i < 4; ++i)
        t[ty * 4 + i][tx] = W[(size_t)(k0 + ty * 4 + i) * N + n0 + tx];
    __syncthreads();
    #pragma unroll
    for (int i = 0; i < 4; ++i)
        Wt[(size_t)(n0 + ty * 4 + i) * K + k0 + tx] = f2bf(t[tx][ty * 4 + i]);
}

// ---------------------------------------------------------------------------
// Build mpi (18432 x 1024 bf16): row b*9+s = bf16(memory[b][s]) (s<8), else x_b[b]
// ---------------------------------------------------------------------------
__global__ __launch_bounds__(256)
void build_mpi(const float* __restrict__ mem, const ushort_t* __restrict__ xb,
               ushort_t* __restrict__ mpi)
{
    size_t i4 = ((size_t)blockIdx.x * 256 + threadIdx.x) * 4;
    if (i4 >= (size_t)18432 * 1024) return;
    int row = (int)(i4 >> 10), col = (int)(i4 & 1023);
    int b = row / 9, s = row - b * 9;
    if (s < 8) {
        float4 v = *(const float4*)(mem + (size_t)b * 8192 + (size_t)s * 1024 + col);
        mpi[i4 + 0] = f2bf(v.x); mpi[i4 + 1] = f2bf(v.y);
        mpi[i4 + 2] = f2bf(v.z); mpi[i4 + 3] = f2bf(v.w);
    } else {
        *(ushort4*)(mpi + i4) = *(const ushort4*)(xb + (size_t)b * 1024 + col);
    }
}

// ---------------------------------------------------------------------------
// Attention (chunk-local): block per (b,h). Writes m1 bf16 only.
// ---------------------------------------------------------------------------
__global__ __launch_bounds__(128)
void attn_kernel(const ushort_t* __restrict__ qkv, const float* __restrict__ mem,
                 ushort_t* __restrict__ m1b)
{
    const int bh = blockIdx.x;
    const int b = bh >> 3, h = bh & 7;
    __shared__ float qs[8][129];
    __shared__ float ks[9][129];
    __shared__ float vs[9][129];
    __shared__ float w[8][9];
    __shared__ float sred[8][9];
    const int tid = threadIdx.x;  // 128
    const float scale = 0.05103103630798288f;  // 384^-0.5

    #pragma unroll
    for (int s = 0; s < 9; ++s) {
        const ushort_t* base = qkv + (size_t)(b * 9 + s) * 3072 + h * 384;
        if (s < 8) qs[s][tid] = bf2f(base[tid]) * scale;
        ks[s][tid] = bf2f(base[128 + tid]);
        vs[s][tid] = bf2f(base[256 + tid]);
    }
    __syncthreads();

    if (tid < 72) {
        const int i = tid / 9, j = tid % 9;
        float sc = 0.f;
        #pragma unroll 8
        for (int d = 0; d < 128; ++d) sc += qs[i][d] * ks[j][d];
        sred[i][j] = sc;
    }
    __syncthreads();

    if (tid < 8) {
        float mx = -1e30f;
        for (int j2 = 0; j2 < 9; ++j2) mx = fmaxf(mx, sred[tid][j2]);
        float e[9], sum = 0.f;
        for (int j2 = 0; j2 < 9; ++j2) { e[j2] = __expf(sred[tid][j2] - mx); sum += e[j2]; }
        float inv = __builtin_amdgcn_rcpf(sum);
        for (int j2 = 0; j2 < 9; ++j2) w[tid][j2] = e[j2] * inv;
    }
    __syncthreads();

    #pragma unroll
    for (int i2 = 0; i2 < 8; ++i2) {
        float acc = 0.f;
        #pragma unroll
        for (int j2 = 0; j2 < 9; ++j2) acc += w[i2][j2] * vs[j2][tid];
        size_t off = (size_t)(b * 8 + i2) * 1024 + (size_t)h * 128 + tid;
        m1b[off] = f2bf(mem[off] + acc);
    }
}

// ---------------------------------------------------------------------------
// gi[b][g] = x_b[b,:] . kernel_gi[:,g] + bias_gi[g]
// ---------------------------------------------------------------------------
__global__ __launch_bounds__(256)
void gi_kernel(const ushort_t* __restrict__ xb, const float* __restrict__ kgi,
               const float* __restrict__ bgi, float* __restrict__ gi)
{
    const int b = blockIdx.x, tid = threadIdx.x;
    float g0 = 0.f, g1 = 0.f;
    for (int k = tid; k < 1024; k += 256) {
        float xv = bf2f(xb[(size_t)b * 1024 + k]);
        g0 += xv * kgi[k * 2];
        g1 += xv * kgi[k * 2 + 1];
    }
    __shared__ float r0[256], r1[256];
    r0[tid] = g0; r1[tid] = g1;
    __syncthreads();
    for (int s = 128; s > 0; s >>= 1) {
        if (tid < s) { r0[tid] += r0[tid + s]; r1[tid] += r1[tid + s]; }
        __syncthreads();
    }
    if (tid == 0) { gi[b * 2] = r0[0] + bgi[0]; gi[b * 2 + 1] = r1[0] + bgi[1]; }
}

// ---------------------------------------------------------------------------
// Gates: per row (b*8+s): ig = sig(tanh(mem).kgm0 + bgm0 + gi0),
//                         fg = sig(tanh(mem).kgm1 + bgm1 + gi1 + 1)
// ---------------------------------------------------------------------------
__global__ __launch_bounds__(256)
void gates_kernel(const float* __restrict__ mem, const float* __restrict__ kgm,
                  const float* __restrict__ bgm, const float* __restrict__ gi,
                  float* __restrict__ igfg)
{
    const int row = blockIdx.x;   // global b*8+s
    const int b = row >> 3;
    const int tid = threadIdx.x;
    const float* mrow = mem + (size_t)row * 1024;
    float g0 = 0.f, g1 = 0.f;
    for (int k = tid; k < 1024; k += 256) {
        float t = fast_tanh(mrow[k]);
        g0 += t * kgm[k * 2];
        g1 += t * kgm[k * 2 + 1];
    }
    __shared__ float r0[256], r1[256];
    r0[tid] = g0; r1[tid] = g1;
    __syncthreads();
    for (int s = 128; s > 0; s >>= 1) {
        if (tid < s) { r0[tid] += r0[tid + s]; r1[tid] += r1[tid + s]; }
        __syncthreads();
    }
    if (tid == 0) {
        igfg[row * 2 + 0] = fast_sigmoid(r0[0] + bgm[0] + gi[b * 2]);
        igfg[row * 2 + 1] = fast_sigmoid(r1[0] + bgm[1] + gi[b * 2 + 1] + 1.0f);
    }
}

// ---------------------------------------------------------------------------
extern "C" void kernel_launch(void* const* d_in, const int* in_sizes, int n_in,
                              void* d_out, int out_size, void* d_ws, size_t ws_size,
                              hipStream_t stream)
{
    const float* inputs     = (const float*)d_in[0];
    const float* memory     = (const float*)d_in[1];
    const float* kernel_qkv = (const float*)d_in[2];
    const float* bias_qkv   = (const float*)d_in[3];
    const float* kernel_gi  = (const float*)d_in[4];
    const float* bias_gi    = (const float*)d_in[5];
    const float* kernel_gm  = (const float*)d_in[6];
    const float* bias_gm    = (const float*)d_in[7];
    const float* kernel_in  = (const float*)d_in[8];
    const float* bias_in    = (const float*)d_in[9];
    const float* mlp_k0     = (const float*)d_in[10];
    const float* mlp_b0     = (const float*)d_in[11];
    const float* mlp_k1     = (const float*)d_in[12];
    const float* mlp_b1     = (const float*)d_in[13];
    float* out = (float*)d_out;

    // ---- workspace carve (bytes) ----
    char* p = (char*)d_ws;
    ushort_t* in_b   = (ushort_t*)p;  p += (size_t)2048 * 1024 * 2;    // 4 MB
    ushort_t* x_b    = (ushort_t*)p;  p += (size_t)2048 * 1024 * 2;    // 4 MB
    ushort_t* wt_in  = (ushort_t*)p;  p += (size_t)1024 * 1024 * 2;    // 2 MB
    ushort_t* wt_qkv = (ushort_t*)p;  p += (size_t)3072 * 1024 * 2;    // 6 MB
    ushort_t* wt_k0  = (ushort_t*)p;  p += (size_t)1024 * 1024 * 2;
    ushort_t* wt_k1  = (ushort_t*)p;  p += (size_t)1024 * 1024 * 2;
    float*    ws_gi  = (float*)p;     p += (size_t)2048 * 2 * 4;
    float*    igfg   = (float*)p;     p += (size_t)16384 * 2 * 4;      // 128 KB
    ushort_t* ws_mpi = (ushort_t*)p;  p += (size_t)18432 * 1024 * 2;   // 36 MB
    ushort_t* m1b    = (ushort_t*)p;  p += (size_t)16384 * 1024 * 2;   // 32 MB
    ushort_t* ws_h   = (ushort_t*)p;  p += (size_t)16384 * 1024 * 2;   // 32 MB
    size_t fixed = (size_t)(p - (char*)d_ws);

    int Bc = 128;
    for (int cand = 2048; cand >= 128; cand >>= 1)
        if (fixed + (size_t)cand * 9 * 3072 * 2 <= ws_size) { Bc = cand; break; }
    ushort_t* ws_qkv = (ushort_t*)p;   // Bc*9*3072 bf16

    // ---- conversions ----
    conv_bf16<<<2048, 256, 0, stream>>>(inputs, in_b, (size_t)2048 * 1024);
    dim3 wtb(32, 8);
    conv_wt<<<dim3(32, 32), wtb, 0, stream>>>(kernel_in, wt_in, 1024, 1024);
    conv_wt<<<dim3(96, 32), wtb, 0, stream>>>(kernel_qkv, wt_qkv, 1024, 3072);
    conv_wt<<<dim3(32, 32), wtb, 0, stream>>>(mlp_k0, wt_k0, 1024, 1024);
    conv_wt<<<dim3(32, 32), wtb, 0, stream>>>(mlp_k1, wt_k1, 1024, 1024);

    // x_b = bf16(inputs @ kernel_in + bias_in)
    gemm_mfma<<<dim3(8, 16), 256, 0, stream>>>(
        in_b, wt_in, bias_in, nullptr, x_b, nullptr, nullptr, nullptr, nullptr,
        2048, 1024, 1024, 0);

    gi_kernel<<<2048, 256, 0, stream>>>(x_b, kernel_gi, bias_gi, ws_gi);
    gates_kernel<<<16384, 256, 0, stream>>>(memory, kernel_gm, bias_gm, ws_gi, igfg);
    build_mpi<<<18432, 256, 0, stream>>>(memory, x_b, ws_mpi);

    // qkv + attention, chunked (qkv scratch is the big buffer)
    const int NC = 2048 / Bc;
    for (int c = 0; c < NC; ++c) {
        const int b0 = c * Bc;
        gemm_mfma<<<dim3(3072 / 128, Bc * 9 / 128), 256, 0, stream>>>(
            ws_mpi + (size_t)b0 * 9 * 1024, wt_qkv, bias_qkv, nullptr, ws_qkv,
            nullptr, nullptr, nullptr, nullptr, Bc * 9, 3072, 1024, 0);
        attn_kernel<<<Bc * 8, 128, 0, stream>>>(
            ws_qkv, memory + (size_t)b0 * 8192, m1b + (size_t)b0 * 8192);
    }

    // h = relu(m1 @ mlp_k0 + mlp_b0), full batch (bf16)
    gemm_mfma<<<dim3(8, 128), 256, 0, stream>>>(
        m1b, wt_k0, mlp_b0, nullptr, ws_h, nullptr, nullptr, nullptr, nullptr,
        16384, 1024, 1024, 1);

    // out = ig*tanh(m1 + h @ mlp_k1 + mlp_b1) + fg*mem, fused epilogue
    gemm_mfma<<<dim3(8, 128), 256, 0, stream>>>(
        ws_h, wt_k1, mlp_b1, nullptr, nullptr, m1b, igfg, memory, out,
        16384, 1024, 1024, 0);
}

// Round 5
// 681.051 us; speedup vs baseline: 1.0344x; 1.0344x over previous
//
#include <hip/hip_runtime.h>
#include <math.h>

// RelationalMemoryCell: B=2048, S=8, H=8, M=1024, QKV=384, TOTAL=3072,
// IN_DIM=1024. fp32 in/out; GEMMs bf16 MFMA (fp32 accumulate).
//
// Pruning: m2[:, :-1] drops the s=8 row => MLP + attention q only for s=0..7.
// Gates (ig/fg) depend only on memory & x => precomputed (fused with mpi
// build); final blend fused into mlp1 epilogue.
// qkv GEMM chunked at Bc=1024: A-chunk (18 MB) stays L2-resident (R3: 2x104us
// beat R4 full-batch 228us).

typedef unsigned short ushort_t;                                  // bf16 bits
typedef short bf16x8_t __attribute__((ext_vector_type(8)));       // MFMA A/B frag
typedef float f32x4_t  __attribute__((ext_vector_type(4)));       // MFMA C/D frag

__device__ __forceinline__ ushort_t f2bf(float f) {               // RNE
    unsigned int u = __float_as_uint(f);
    u += 0x7fff + ((u >> 16) & 1);
    return (ushort_t)(u >> 16);
}
__device__ __forceinline__ float bf2f(ushort_t h) {
    return __uint_as_float(((unsigned int)h) << 16);
}
__device__ __forceinline__ float fast_tanh(float x) {             // sat-safe
    float e = __expf(2.0f * x);
    return 1.0f - 2.0f * __builtin_amdgcn_rcpf(e + 1.0f);
}
__device__ __forceinline__ float fast_sigmoid(float x) {
    return __builtin_amdgcn_rcpf(1.0f + __expf(-x));
}

__device__ __forceinline__ void load_lds_16(const void* g, void* l) {
    __builtin_amdgcn_global_load_lds(
        (const __attribute__((address_space(1))) void*)g,
        (__attribute__((address_space(3))) void*)l, 16, 0, 0);
}

// ---------------------------------------------------------------------------
// bf16 MFMA GEMM, 128x128 tile, BK=32, 4 waves, 4x4 x mfma_16x16x32_bf16.
// A: MxK bf16 row-major. Wt: NxK bf16 (pre-transposed W). XOR-swizzled LDS.
// Epilogue modes: outp -> ig*tanh(v)+fg*mem ; Cb -> bf16 ; Cf -> fp32.
// ---------------------------------------------------------------------------
__global__ __launch_bounds__(256)
void gemm_mfma(const ushort_t* __restrict__ A, const ushort_t* __restrict__ Wt,
               const float* __restrict__ bias, float* __restrict__ Cf,
               ushort_t* __restrict__ Cb, const ushort_t* __restrict__ resb,
               const float* __restrict__ igfg, const float* __restrict__ memf,
               float* __restrict__ outp, int M, int N, int K, int relu)
{
    __shared__ __align__(16) ushort_t As[128 * 32];
    __shared__ __align__(16) ushort_t Bs[128 * 32];
    const int tid  = threadIdx.x;
    const int wave = tid >> 6, lane = tid & 63;
    const int wr = (wave >> 1) * 64;
    const int wc = (wave & 1)  * 64;
    const int lrow  = lane & 15;
    const int lquad = lane >> 4;
    const int rowBase = blockIdx.y * 128;
    const int colBase = blockIdx.x * 128;

    f32x4_t acc[4][4] = {};

    for (int k0 = 0; k0 < K; k0 += 32) {
        #pragma unroll
        for (int i = 0; i < 2; ++i) {
            int e    = i * 256 + tid;
            int row  = e >> 2;
            int c    = (e & 3) ^ ((row >> 1) & 3);
            const ushort_t* ga = A  + (size_t)(rowBase + row) * K + k0 + c * 8;
            const ushort_t* gb = Wt + (size_t)(colBase + row) * K + k0 + c * 8;
            load_lds_16(ga, &As[e * 8]);
            load_lds_16(gb, &Bs[e * 8]);
        }
        __syncthreads();

        bf16x8_t af[4], bfr[4];
        #pragma unroll
        for (int t = 0; t < 4; ++t) {
            int ma = wr + t * 16 + lrow;
            int pa = lquad ^ ((ma >> 1) & 3);
            af[t]  = *(const bf16x8_t*)&As[ma * 32 + pa * 8];
            int nb = wc + t * 16 + lrow;
            int pb = lquad ^ ((nb >> 1) & 3);
            bfr[t] = *(const bf16x8_t*)&Bs[nb * 32 + pb * 8];
        }
        #pragma unroll
        for (int mi = 0; mi < 4; ++mi)
            #pragma unroll
            for (int ni = 0; ni < 4; ++ni)
                acc[mi][ni] = __builtin_amdgcn_mfma_f32_16x16x32_bf16(
                    af[mi], bfr[ni], acc[mi][ni], 0, 0, 0);
        __syncthreads();
    }

    // D layout: col = lane&15, row = lquad*4 + r   [m89/m91]
    #pragma unroll
    for (int mi = 0; mi < 4; ++mi) {
        #pragma unroll
        for (int ni = 0; ni < 4; ++ni) {
            int col = colBase + wc + ni * 16 + lrow;
            float bv = bias[col];
            #pragma unroll
            for (int r = 0; r < 4; ++r) {
                int row = rowBase + wr + mi * 16 + lquad * 4 + r;
                size_t idx = (size_t)row * N + col;
                float v = acc[mi][ni][r] + bv;
                if (resb) v += bf2f(resb[idx]);
                if (relu) v = fmaxf(v, 0.f);
                if (outp) {
                    float ig = igfg[row * 2], fg = igfg[row * 2 + 1];
                    outp[idx] = ig * fast_tanh(v) + fg * memf[idx];
                } else if (Cb) {
                    Cb[idx] = f2bf(v);
                } else {
                    Cf[idx] = v;
                }
            }
        }
    }
}

// ---------------------------------------------------------------------------
// fp32 -> bf16 elementwise
// ---------------------------------------------------------------------------
__global__ __launch_bounds__(256)
void conv_bf16(const float* __restrict__ in, ushort_t* __restrict__ out, size_t n)
{
    size_t i = ((size_t)blockIdx.x * 256 + threadIdx.x) * 4;
    if (i >= n) return;
    float4 v = *(const float4*)(in + i);
    out[i + 0] = f2bf(v.x); out[i + 1] = f2bf(v.y);
    out[i + 2] = f2bf(v.z); out[i + 3] = f2bf(v.w);
}

// ---------------------------------------------------------------------------
// Weight transpose+convert: Wt[n][k] = bf16(W[k][n])
// ---------------------------------------------------------------------------
__global__ __launch_bounds__(256)
void conv_wt(const float* __restrict__ W, ushort_t* __restrict__ Wt, int K, int N)
{
    __shared__ float t[32][33];
    const int n0 = blockIdx.x * 32, k0 = blockIdx.y * 32;
    const int tx = threadIdx.x, ty = threadIdx.y;   // (32, 8)
    #pragma unroll
    for (int i = 0; i < 4; ++i)
        t[ty * 4 + i][tx] = W[(size_t)(k0 + ty * 4 + i) * N + n0 + tx];
    __syncthreads();
    #pragma unroll
    for (int i = 0; i < 4; ++i)
        Wt[(size_t)(n0 + ty * 4 + i) * K + k0 + tx] = f2bf(t[tx][ty * 4 + i]);
}

// ---------------------------------------------------------------------------
// prep: block per mpi row (b*9+s, 18432). s<8: convert mem row -> mpi bf16 AND
// reduce tanh(mem).kgm -> igfg (fused gates). s==8: copy x_b row into mpi.
// ---------------------------------------------------------------------------
__global__ __launch_bounds__(256)
void prep_kernel(const float* __restrict__ mem, const ushort_t* __restrict__ xb,
                 const float* __restrict__ kgm, const float* __restrict__ bgm,
                 const float* __restrict__ gi, ushort_t* __restrict__ mpi,
                 float* __restrict__ igfg)
{
    const int row = blockIdx.x;            // b*9+s
    const int tid = threadIdx.x;
    const int b = row / 9, s = row - b * 9;
    if (s == 8) {
        ((ushort4*)(mpi + (size_t)row * 1024))[tid] =
            ((const ushort4*)(xb + (size_t)b * 1024))[tid];
        return;
    }
    const float* mrow = mem + ((size_t)b * 8 + s) * 1024;
    float4 v = ((const float4*)mrow)[tid];
    ushort4 o;
    o.x = f2bf(v.x); o.y = f2bf(v.y); o.z = f2bf(v.z); o.w = f2bf(v.w);
    ((ushort4*)(mpi + (size_t)row * 1024))[tid] = o;
    // kgm[k][2]: float4 pair covers k = 4tid..4tid+3
    float4 k0 = ((const float4*)kgm)[tid * 2];
    float4 k1 = ((const float4*)kgm)[tid * 2 + 1];
    float t0 = fast_tanh(v.x), t1 = fast_tanh(v.y);
    float t2 = fast_tanh(v.z), t3 = fast_tanh(v.w);
    float g0 = t0 * k0.x + t1 * k0.z + t2 * k1.x + t3 * k1.z;
    float g1 = t0 * k0.y + t1 * k0.w + t2 * k1.y + t3 * k1.w;
    #pragma unroll
    for (int m = 1; m <= 32; m <<= 1) {
        g0 += __shfl_xor(g0, m);
        g1 += __shfl_xor(g1, m);
    }
    __shared__ float wg[4][2];
    if ((tid & 63) == 0) { wg[tid >> 6][0] = g0; wg[tid >> 6][1] = g1; }
    __syncthreads();
    if (tid == 0) {
        float G0 = wg[0][0] + wg[1][0] + wg[2][0] + wg[3][0];
        float G1 = wg[0][1] + wg[1][1] + wg[2][1] + wg[3][1];
        int orow = b * 8 + s;
        igfg[orow * 2 + 0] = fast_sigmoid(G0 + bgm[0] + gi[b * 2 + 0]);
        igfg[orow * 2 + 1] = fast_sigmoid(G1 + bgm[1] + gi[b * 2 + 1] + 1.0f);
    }
}

// ---------------------------------------------------------------------------
// MFMA attention: block per (b,h) chunk-local, 256 thr.
// S = Q.K^T via 4x mfma_16x16x32_bf16 (wave 0, frags straight from global qkv;
// q rows duplicated m&7, k tokens clamped min(n,8); masked in softmax).
// P -> LDS bf16 (stride 40: 2-way banks). V^T staged zero-padded in LDS.
// PV: each wave 32 d-cols = 2 MFMAs. Epilogue: m1b = bf16(att + mem).
// ---------------------------------------------------------------------------
__global__ __launch_bounds__(256)
void attn_kernel(const ushort_t* __restrict__ qkv, const float* __restrict__ mem,
                 ushort_t* __restrict__ m1b)
{
    const int bh = blockIdx.x;
    const int b = bh >> 3, h = bh & 7;
    constexpr int VS = 40;                            // padded j-stride (elems)
    __shared__ __align__(16) ushort_t vt[128 * VS];   // V^T [d][j], j padded to 32
    __shared__ __align__(16) ushort_t pw[16 * VS];    // P [i][j], j padded to 32
    const int tid  = threadIdx.x;
    const int lane = tid & 63, wave = tid >> 6;
    const int quad = lane >> 4;
    const size_t qrow0 = (size_t)b * 9;

    // zero LDS (j-pad must be 0), then stage V^T
    {
        unsigned long long* z = (unsigned long long*)vt;
        #pragma unroll
        for (int i = 0; i < 5; ++i) z[tid + i * 256] = 0ull;   // 1280 ull
        if (tid < 160) ((unsigned long long*)pw)[tid] = 0ull;  // 160 ull
    }
    __syncthreads();
    for (int c = tid; c < 9 * 128; c += 256) {
        int j = c >> 7, d = c & 127;
        vt[d * VS + j] = qkv[(qrow0 + j) * 3072 + (size_t)h * 384 + 256 + d];
    }

    f32x4_t sacc = {0.f, 0.f, 0.f, 0.f};
    if (wave == 0) {
        const int m  = lane & 7;                       // q row (dup 8..15)
        const int n  = lane & 15;
        const int nc = n > 8 ? 8 : n;                  // k token clamp
        const ushort_t* qb = qkv + (qrow0 + m)  * 3072 + (size_t)h * 384 + quad * 8;
        const ushort_t* kb = qkv + (qrow0 + nc) * 3072 + (size_t)h * 384 + 128 + quad * 8;
        #pragma unroll
        for (int t = 0; t < 4; ++t) {
            bf16x8_t aq = *(const bf16x8_t*)(qb + t * 32);
            bf16x8_t bk = *(const bf16x8_t*)(kb + t * 32);
            sacc = __builtin_amdgcn_mfma_f32_16x16x32_bf16(aq, bk, sacc, 0, 0, 0);
        }
    }
    __syncthreads();   // vt + pw zeros ready

    if (wave == 0) {
        const int j = lane & 15;
        const float scale = 0.05103103630798288f;      // 384^-0.5
        #pragma unroll
        for (int r = 0; r < 4; ++r) {
            float sv = (j < 9) ? sacc[r] * scale : -1e30f;
            float mx = sv;
            mx = fmaxf(mx, __shfl_xor(mx, 1));
            mx = fmaxf(mx, __shfl_xor(mx, 2));
            mx = fmaxf(mx, __shfl_xor(mx, 4));
            mx = fmaxf(mx, __shfl_xor(mx, 8));
            float e = (j < 9) ? __expf(sv - mx) : 0.f;
            float sum = e;
            sum += __shfl_xor(sum, 1);
            sum += __shfl_xor(sum, 2);
            sum += __shfl_xor(sum, 4);
            sum += __shfl_xor(sum, 8);
            pw[(quad * 4 + r) * VS + j] = f2bf(e * __builtin_amdgcn_rcpf(sum));
        }
    }
    __syncthreads();   // pw ready

    // PV: wave w -> d in [32w, 32w+32)
    {
        const int n  = lane & 15;
        const int d0 = wave * 32;
        bf16x8_t pa = *(const bf16x8_t*)&pw[n * VS + quad * 8];   // A: P[m=n][k]
        #pragma unroll
        for (int g = 0; g < 2; ++g) {
            int d = d0 + g * 16 + n;
            bf16x8_t vb = *(const bf16x8_t*)&vt[d * VS + quad * 8];
            f32x4_t o = {0.f, 0.f, 0.f, 0.f};
            o = __builtin_amdgcn_mfma_f32_16x16x32_bf16(pa, vb, o, 0, 0, 0);
            #pragma unroll
            for (int r = 0; r < 4; ++r) {
                int i = quad * 4 + r;
                if (i < 8) {
                    size_t idx = ((size_t)b * 8 + i) * 1024 + (size_t)h * 128 + d;
                    m1b[idx] = f2bf(o[r] + mem[idx]);
                }
            }
        }
    }
}

// ---------------------------------------------------------------------------
// gi[b][g] = x_b[b,:] . kernel_gi[:,g] + bias_gi[g]
// ---------------------------------------------------------------------------
__global__ __launch_bounds__(256)
void gi_kernel(const ushort_t* __restrict__ xb, const float* __restrict__ kgi,
               const float* __restrict__ bgi, float* __restrict__ gi)
{
    const int b = blockIdx.x, tid = threadIdx.x;
    float g0 = 0.f, g1 = 0.f;
    for (int k = tid; k < 1024; k += 256) {
        float xv = bf2f(xb[(size_t)b * 1024 + k]);
        g0 += xv * kgi[k * 2];
        g1 += xv * kgi[k * 2 + 1];
    }
    #pragma unroll
    for (int m = 1; m <= 32; m <<= 1) {
        g0 += __shfl_xor(g0, m);
        g1 += __shfl_xor(g1, m);
    }
    __shared__ float wg[4][2];
    if ((tid & 63) == 0) { wg[tid >> 6][0] = g0; wg[tid >> 6][1] = g1; }
    __syncthreads();
    if (tid == 0) {
        gi[b * 2 + 0] = wg[0][0] + wg[1][0] + wg[2][0] + wg[3][0] + bgi[0];
        gi[b * 2 + 1] = wg[0][1] + wg[1][1] + wg[2][1] + wg[3][1] + bgi[1];
    }
}

// ---------------------------------------------------------------------------
extern "C" void kernel_launch(void* const* d_in, const int* in_sizes, int n_in,
                              void* d_out, int out_size, void* d_ws, size_t ws_size,
                              hipStream_t stream)
{
    const float* inputs     = (const float*)d_in[0];
    const float* memory     = (const float*)d_in[1];
    const float* kernel_qkv = (const float*)d_in[2];
    const float* bias_qkv   = (const float*)d_in[3];
    const float* kernel_gi  = (const float*)d_in[4];
    const float* bias_gi    = (const float*)d_in[5];
    const float* kernel_gm  = (const float*)d_in[6];
    const float* bias_gm    = (const float*)d_in[7];
    const float* kernel_in  = (const float*)d_in[8];
    const float* bias_in    = (const float*)d_in[9];
    const float* mlp_k0     = (const float*)d_in[10];
    const float* mlp_b0     = (const float*)d_in[11];
    const float* mlp_k1     = (const float*)d_in[12];
    const float* mlp_b1     = (const float*)d_in[13];
    float* out = (float*)d_out;

    // ---- workspace carve (bytes) ----
    char* p = (char*)d_ws;
    ushort_t* in_b   = (ushort_t*)p;  p += (size_t)2048 * 1024 * 2;    // 4 MB
    ushort_t* x_b    = (ushort_t*)p;  p += (size_t)2048 * 1024 * 2;    // 4 MB
    ushort_t* wt_in  = (ushort_t*)p;  p += (size_t)1024 * 1024 * 2;    // 2 MB
    ushort_t* wt_qkv = (ushort_t*)p;  p += (size_t)3072 * 1024 * 2;    // 6 MB
    ushort_t* wt_k0  = (ushort_t*)p;  p += (size_t)1024 * 1024 * 2;
    ushort_t* wt_k1  = (ushort_t*)p;  p += (size_t)1024 * 1024 * 2;
    float*    ws_gi  = (float*)p;     p += (size_t)2048 * 2 * 4;
    float*    igfg   = (float*)p;     p += (size_t)16384 * 2 * 4;      // 128 KB
    ushort_t* ws_mpi = (ushort_t*)p;  p += (size_t)18432 * 1024 * 2;   // 36 MB
    ushort_t* m1b    = (ushort_t*)p;  p += (size_t)16384 * 1024 * 2;   // 32 MB
    ushort_t* ws_h   = (ushort_t*)p;  p += (size_t)16384 * 1024 * 2;   // 32 MB
    size_t fixed = (size_t)(p - (char*)d_ws);

    int Bc = 128;   // cap at 1024: chunked beats full batch (L2 residency)
    for (int cand = 1024; cand >= 128; cand >>= 1)
        if (fixed + (size_t)cand * 9 * 3072 * 2 <= ws_size) { Bc = cand; break; }
    ushort_t* ws_qkv = (ushort_t*)p;   // Bc*9*3072 bf16

    // ---- conversions ----
    conv_bf16<<<2048, 256, 0, stream>>>(inputs, in_b, (size_t)2048 * 1024);
    dim3 wtb(32, 8);
    conv_wt<<<dim3(32, 32), wtb, 0, stream>>>(kernel_in, wt_in, 1024, 1024);
    conv_wt<<<dim3(96, 32), wtb, 0, stream>>>(kernel_qkv, wt_qkv, 1024, 3072);
    conv_wt<<<dim3(32, 32), wtb, 0, stream>>>(mlp_k0, wt_k0, 1024, 1024);
    conv_wt<<<dim3(32, 32), wtb, 0, stream>>>(mlp_k1, wt_k1, 1024, 1024);

    // x_b = bf16(inputs @ kernel_in + bias_in)
    gemm_mfma<<<dim3(8, 16), 256, 0, stream>>>(
        in_b, wt_in, bias_in, nullptr, x_b, nullptr, nullptr, nullptr, nullptr,
        2048, 1024, 1024, 0);

    gi_kernel<<<2048, 256, 0, stream>>>(x_b, kernel_gi, bias_gi, ws_gi);
    prep_kernel<<<18432, 256, 0, stream>>>(memory, x_b, kernel_gm, bias_gm,
                                           ws_gi, ws_mpi, igfg);

    // qkv + attention, chunked
    const int NC = 2048 / Bc;
    for (int c = 0; c < NC; ++c) {
        const int b0 = c * Bc;
        gemm_mfma<<<dim3(3072 / 128, Bc * 9 / 128), 256, 0, stream>>>(
            ws_mpi + (size_t)b0 * 9 * 1024, wt_qkv, bias_qkv, nullptr, ws_qkv,
            nullptr, nullptr, nullptr, nullptr, Bc * 9, 3072, 1024, 0);
        attn_kernel<<<Bc * 8, 256, 0, stream>>>(
            ws_qkv, memory + (size_t)b0 * 8192, m1b + (size_t)b0 * 8192);
    }

    // h = relu(m1 @ mlp_k0 + mlp_b0), full batch (bf16)
    gemm_mfma<<<dim3(8, 128), 256, 0, stream>>>(
        m1b, wt_k0, mlp_b0, nullptr, ws_h, nullptr, nullptr, nullptr, nullptr,
        16384, 1024, 1024, 1);

    // out = ig*tanh(m1 + h @ mlp_k1 + mlp_b1) + fg*mem, fused epilogue
    gemm_mfma<<<dim3(8, 128), 256, 0, stream>>>(
        ws_h, wt_k1, mlp_b1, nullptr, nullptr, m1b, igfg, memory, out,
        16384, 1024, 1024, 0);
}

// Round 6
// 652.019 us; speedup vs baseline: 1.0805x; 1.0445x over previous
//
#include <hip/hip_runtime.h>
#include <math.h>

// RelationalMemoryCell: B=2048, S=8, H=8, M=1024, QKV=384, TOTAL=3072,
// IN_DIM=1024. fp32 in/out; GEMMs bf16 MFMA (fp32 accumulate).
//
// Pruning: m2[:, :-1] drops the s=8 row => MLP + attention q only for s=0..7.
// Gates precomputed (fused into prep); final blend fused into mlp1 epilogue.
// qkv chunked at Bc=1024 (L2 residency, R3 evidence).
// R6: XCD swizzle — row-tile's col-blocks at stride-8 linear ids => same XCD
// under %8 round-robin => A-tile fetched once per XCD, not 8-24x.
// R6: memory re-reads in attn/mlp1 epilogues use bf16 rows from ws_mpi.

typedef unsigned short ushort_t;                                  // bf16 bits
typedef short bf16x8_t __attribute__((ext_vector_type(8)));       // MFMA A/B frag
typedef float f32x4_t  __attribute__((ext_vector_type(4)));       // MFMA C/D frag

__device__ __forceinline__ ushort_t f2bf(float f) {               // RNE
    unsigned int u = __float_as_uint(f);
    u += 0x7fff + ((u >> 16) & 1);
    return (ushort_t)(u >> 16);
}
__device__ __forceinline__ float bf2f(ushort_t h) {
    return __uint_as_float(((unsigned int)h) << 16);
}
__device__ __forceinline__ float fast_tanh(float x) {             // sat-safe
    float e = __expf(2.0f * x);
    return 1.0f - 2.0f * __builtin_amdgcn_rcpf(e + 1.0f);
}
__device__ __forceinline__ float fast_sigmoid(float x) {
    return __builtin_amdgcn_rcpf(1.0f + __expf(-x));
}

__device__ __forceinline__ void load_lds_16(const void* g, void* l) {
    __builtin_amdgcn_global_load_lds(
        (const __attribute__((address_space(1))) void*)g,
        (__attribute__((address_space(3))) void*)l, 16, 0, 0);
}

// ---------------------------------------------------------------------------
// bf16 MFMA GEMM, 128x128 tile, BK=32, 4 waves, 4x4 x mfma_16x16x32_bf16.
// A: MxK bf16 row-major. Wt: NxK bf16 (pre-transposed W). XOR-swizzled LDS.
// 1D grid = ncol*nrow tiles; XCD swizzle when nrow%8==0.
// Epilogue modes: outp -> ig*tanh(v+res)+fg*bf16mem ; Cb -> bf16 ; Cf -> fp32.
// memb (bf16 memory rows, mpi layout): row b*8+s -> mpi row b*9+s = row+(row>>3).
// ---------------------------------------------------------------------------
__global__ __launch_bounds__(256)
void gemm_mfma(const ushort_t* __restrict__ A, const ushort_t* __restrict__ Wt,
               const float* __restrict__ bias, float* __restrict__ Cf,
               ushort_t* __restrict__ Cb, const ushort_t* __restrict__ resb,
               const float* __restrict__ igfg, const ushort_t* __restrict__ memb,
               float* __restrict__ outp, int N, int K, int relu,
               int ncol, int nrow)
{
    __shared__ __align__(16) ushort_t As[128 * 32];
    __shared__ __align__(16) ushort_t Bs[128 * 32];
    const int tid  = threadIdx.x;
    const int wave = tid >> 6, lane = tid & 63;
    const int wr = (wave >> 1) * 64;
    const int wc = (wave & 1)  * 64;
    const int lrow  = lane & 15;
    const int lquad = lane >> 4;

    // XCD-aware tile decode: a row-tile's ncol blocks sit at stride-8 linear
    // ids => same XCD under %8 round-robin => A-tile fetched ~once per XCD.
    int l = blockIdx.x, rT, cT;
    if ((nrow & 7) == 0) {
        int group = l / (8 * ncol);
        int w     = l - group * 8 * ncol;
        rT = group * 8 + (w & 7);
        cT = w >> 3;
    } else {
        rT = l / ncol;
        cT = l - rT * ncol;
    }
    const int rowBase = rT * 128;
    const int colBase = cT * 128;

    f32x4_t acc[4][4] = {};

    for (int k0 = 0; k0 < K; k0 += 32) {
        #pragma unroll
        for (int i = 0; i < 2; ++i) {
            int e    = i * 256 + tid;
            int row  = e >> 2;
            int c    = (e & 3) ^ ((row >> 1) & 3);
            const ushort_t* ga = A  + (size_t)(rowBase + row) * K + k0 + c * 8;
            const ushort_t* gb = Wt + (size_t)(colBase + row) * K + k0 + c * 8;
            load_lds_16(ga, &As[e * 8]);
            load_lds_16(gb, &Bs[e * 8]);
        }
        __syncthreads();

        bf16x8_t af[4], bfr[4];
        #pragma unroll
        for (int t = 0; t < 4; ++t) {
            int ma = wr + t * 16 + lrow;
            int pa = lquad ^ ((ma >> 1) & 3);
            af[t]  = *(const bf16x8_t*)&As[ma * 32 + pa * 8];
            int nb = wc + t * 16 + lrow;
            int pb = lquad ^ ((nb >> 1) & 3);
            bfr[t] = *(const bf16x8_t*)&Bs[nb * 32 + pb * 8];
        }
        #pragma unroll
        for (int mi = 0; mi < 4; ++mi)
            #pragma unroll
            for (int ni = 0; ni < 4; ++ni)
                acc[mi][ni] = __builtin_amdgcn_mfma_f32_16x16x32_bf16(
                    af[mi], bfr[ni], acc[mi][ni], 0, 0, 0);
        __syncthreads();
    }

    // D layout: col = lane&15, row = lquad*4 + r   [m89/m91]
    #pragma unroll
    for (int mi = 0; mi < 4; ++mi) {
        #pragma unroll
        for (int ni = 0; ni < 4; ++ni) {
            int col = colBase + wc + ni * 16 + lrow;
            float bv = bias[col];
            #pragma unroll
            for (int r = 0; r < 4; ++r) {
                int row = rowBase + wr + mi * 16 + lquad * 4 + r;
                size_t idx = (size_t)row * N + col;
                float v = acc[mi][ni][r] + bv;
                if (resb) v += bf2f(resb[idx]);
                if (relu) v = fmaxf(v, 0.f);
                if (outp) {
                    float ig = igfg[row * 2], fg = igfg[row * 2 + 1];
                    float mv = bf2f(memb[(size_t)(row + (row >> 3)) * N + col]);
                    outp[idx] = ig * fast_tanh(v) + fg * mv;
                } else if (Cb) {
                    Cb[idx] = f2bf(v);
                } else {
                    Cf[idx] = v;
                }
            }
        }
    }
}

// ---------------------------------------------------------------------------
// fp32 -> bf16 elementwise
// ---------------------------------------------------------------------------
__global__ __launch_bounds__(256)
void conv_bf16(const float* __restrict__ in, ushort_t* __restrict__ out, size_t n)
{
    size_t i = ((size_t)blockIdx.x * 256 + threadIdx.x) * 4;
    if (i >= n) return;
    float4 v = *(const float4*)(in + i);
    out[i + 0] = f2bf(v.x); out[i + 1] = f2bf(v.y);
    out[i + 2] = f2bf(v.z); out[i + 3] = f2bf(v.w);
}

// ---------------------------------------------------------------------------
// Weight transpose+convert: Wt[n][k] = bf16(W[k][n])
// ---------------------------------------------------------------------------
__global__ __launch_bounds__(256)
void conv_wt(const float* __restrict__ W, ushort_t* __restrict__ Wt, int K, int N)
{
    __shared__ float t[32][33];
    const int n0 = blockIdx.x * 32, k0 = blockIdx.y * 32;
    const int tx = threadIdx.x, ty = threadIdx.y;   // (32, 8)
    #pragma unroll
    for (int i = 0; i < 4; ++i)
        t[ty * 4 + i][tx] = W[(size_t)(k0 + ty * 4 + i) * N + n0 + tx];
    __syncthreads();
    #pragma unroll
    for (int i = 0; i < 4; ++i)
        Wt[(size_t)(n0 + ty * 4 + i) * K + k0 + tx] = f2bf(t[tx][ty * 4 + i]);
}

// ---------------------------------------------------------------------------
// prep: block per mpi row (b*9+s). s<8: mem row -> mpi bf16 + fused gates
// reduction tanh(mem).kgm -> igfg. s==8: copy x_b row.
// ---------------------------------------------------------------------------
__global__ __launch_bounds__(256)
void prep_kernel(const float* __restrict__ mem, const ushort_t* __restrict__ xb,
                 const float* __restrict__ kgm, const float* __restrict__ bgm,
                 const float* __restrict__ gi, ushort_t* __restrict__ mpi,
                 float* __restrict__ igfg)
{
    const int row = blockIdx.x;            // b*9+s
    const int tid = threadIdx.x;
    const int b = row / 9, s = row - b * 9;
    if (s == 8) {
        ((ushort4*)(mpi + (size_t)row * 1024))[tid] =
            ((const ushort4*)(xb + (size_t)b * 1024))[tid];
        return;
    }
    const float* mrow = mem + ((size_t)b * 8 + s) * 1024;
    float4 v = ((const float4*)mrow)[tid];
    ushort4 o;
    o.x = f2bf(v.x); o.y = f2bf(v.y); o.z = f2bf(v.z); o.w = f2bf(v.w);
    ((ushort4*)(mpi + (size_t)row * 1024))[tid] = o;
    float4 k0 = ((const float4*)kgm)[tid * 2];
    float4 k1 = ((const float4*)kgm)[tid * 2 + 1];
    float t0 = fast_tanh(v.x), t1 = fast_tanh(v.y);
    float t2 = fast_tanh(v.z), t3 = fast_tanh(v.w);
    float g0 = t0 * k0.x + t1 * k0.z + t2 * k1.x + t3 * k1.z;
    float g1 = t0 * k0.y + t1 * k0.w + t2 * k1.y + t3 * k1.w;
    #pragma unroll
    for (int m = 1; m <= 32; m <<= 1) {
        g0 += __shfl_xor(g0, m);
        g1 += __shfl_xor(g1, m);
    }
    __shared__ float wg[4][2];
    if ((tid & 63) == 0) { wg[tid >> 6][0] = g0; wg[tid >> 6][1] = g1; }
    __syncthreads();
    if (tid == 0) {
        float G0 = wg[0][0] + wg[1][0] + wg[2][0] + wg[3][0];
        float G1 = wg[0][1] + wg[1][1] + wg[2][1] + wg[3][1];
        int orow = b * 8 + s;
        igfg[orow * 2 + 0] = fast_sigmoid(G0 + bgm[0] + gi[b * 2 + 0]);
        igfg[orow * 2 + 1] = fast_sigmoid(G1 + bgm[1] + gi[b * 2 + 1] + 1.0f);
    }
}

// ---------------------------------------------------------------------------
// MFMA attention: block per (b,h) chunk-local, 256 thr. Residual from mpi bf16.
// ---------------------------------------------------------------------------
__global__ __launch_bounds__(256)
void attn_kernel(const ushort_t* __restrict__ qkv, const ushort_t* __restrict__ mpib,
                 ushort_t* __restrict__ m1b)
{
    const int bh = blockIdx.x;
    const int b = bh >> 3, h = bh & 7;
    constexpr int VS = 40;                            // padded j-stride
    __shared__ __align__(16) ushort_t vt[128 * VS];   // V^T [d][j]
    __shared__ __align__(16) ushort_t pw[16 * VS];    // P [i][j]
    const int tid  = threadIdx.x;
    const int lane = tid & 63, wave = tid >> 6;
    const int quad = lane >> 4;
    const size_t qrow0 = (size_t)b * 9;

    {
        unsigned long long* z = (unsigned long long*)vt;
        #pragma unroll
        for (int i = 0; i < 5; ++i) z[tid + i * 256] = 0ull;
        if (tid < 160) ((unsigned long long*)pw)[tid] = 0ull;
    }
    __syncthreads();
    for (int c = tid; c < 9 * 128; c += 256) {
        int j = c >> 7, d = c & 127;
        vt[d * VS + j] = qkv[(qrow0 + j) * 3072 + (size_t)h * 384 + 256 + d];
    }

    f32x4_t sacc = {0.f, 0.f, 0.f, 0.f};
    if (wave == 0) {
        const int m  = lane & 7;
        const int n  = lane & 15;
        const int nc = n > 8 ? 8 : n;
        const ushort_t* qb = qkv + (qrow0 + m)  * 3072 + (size_t)h * 384 + quad * 8;
        const ushort_t* kb = qkv + (qrow0 + nc) * 3072 + (size_t)h * 384 + 128 + quad * 8;
        #pragma unroll
        for (int t = 0; t < 4; ++t) {
            bf16x8_t aq = *(const bf16x8_t*)(qb + t * 32);
            bf16x8_t bk = *(const bf16x8_t*)(kb + t * 32);
            sacc = __builtin_amdgcn_mfma_f32_16x16x32_bf16(aq, bk, sacc, 0, 0, 0);
        }
    }
    __syncthreads();

    if (wave == 0) {
        const int j = lane & 15;
        const float scale = 0.05103103630798288f;      // 384^-0.5
        #pragma unroll
        for (int r = 0; r < 4; ++r) {
            float sv = (j < 9) ? sacc[r] * scale : -1e30f;
            float mx = sv;
            mx = fmaxf(mx, __shfl_xor(mx, 1));
            mx = fmaxf(mx, __shfl_xor(mx, 2));
            mx = fmaxf(mx, __shfl_xor(mx, 4));
            mx = fmaxf(mx, __shfl_xor(mx, 8));
            float e = (j < 9) ? __expf(sv - mx) : 0.f;
            float sum = e;
            sum += __shfl_xor(sum, 1);
            sum += __shfl_xor(sum, 2);
            sum += __shfl_xor(sum, 4);
            sum += __shfl_xor(sum, 8);
            pw[(quad * 4 + r) * VS + j] = f2bf(e * __builtin_amdgcn_rcpf(sum));
        }
    }
    __syncthreads();

    {
        const int n  = lane & 15;
        const int d0 = wave * 32;
        bf16x8_t pa = *(const bf16x8_t*)&pw[n * VS + quad * 8];
        #pragma unroll
        for (int g = 0; g < 2; ++g) {
            int d = d0 + g * 16 + n;
            bf16x8_t vb = *(const bf16x8_t*)&vt[d * VS + quad * 8];
            f32x4_t o = {0.f, 0.f, 0.f, 0.f};
            o = __builtin_amdgcn_mfma_f32_16x16x32_bf16(pa, vb, o, 0, 0, 0);
            #pragma unroll
            for (int r = 0; r < 4; ++r) {
                int i = quad * 4 + r;
                if (i < 8) {
                    float mv = bf2f(mpib[((size_t)b * 9 + i) * 1024 + (size_t)h * 128 + d]);
                    size_t idx = ((size_t)b * 8 + i) * 1024 + (size_t)h * 128 + d;
                    m1b[idx] = f2bf(o[r] + mv);
                }
            }
        }
    }
}

// ---------------------------------------------------------------------------
// gi[b][g] = x_b[b,:] . kernel_gi[:,g] + bias_gi[g]
// ---------------------------------------------------------------------------
__global__ __launch_bounds__(256)
void gi_kernel(const ushort_t* __restrict__ xb, const float* __restrict__ kgi,
               const float* __restrict__ bgi, float* __restrict__ gi)
{
    const int b = blockIdx.x, tid = threadIdx.x;
    float g0 = 0.f, g1 = 0.f;
    for (int k = tid; k < 1024; k += 256) {
        float xv = bf2f(xb[(size_t)b * 1024 + k]);
        g0 += xv * kgi[k * 2];
        g1 += xv * kgi[k * 2 + 1];
    }
    #pragma unroll
    for (int m = 1; m <= 32; m <<= 1) {
        g0 += __shfl_xor(g0, m);
        g1 += __shfl_xor(g1, m);
    }
    __shared__ float wg[4][2];
    if ((tid & 63) == 0) { wg[tid >> 6][0] = g0; wg[tid >> 6][1] = g1; }
    __syncthreads();
    if (tid == 0) {
        gi[b * 2 + 0] = wg[0][0] + wg[1][0] + wg[2][0] + wg[3][0] + bgi[0];
        gi[b * 2 + 1] = wg[0][1] + wg[1][1] + wg[2][1] + wg[3][1] + bgi[1];
    }
}

// ---------------------------------------------------------------------------
extern "C" void kernel_launch(void* const* d_in, const int* in_sizes, int n_in,
                              void* d_out, int out_size, void* d_ws, size_t ws_size,
                              hipStream_t stream)
{
    const float* inputs     = (const float*)d_in[0];
    const float* memory     = (const float*)d_in[1];
    const float* kernel_qkv = (const float*)d_in[2];
    const float* bias_qkv   = (const float*)d_in[3];
    const float* kernel_gi  = (const float*)d_in[4];
    const float* bias_gi    = (const float*)d_in[5];
    const float* kernel_gm  = (const float*)d_in[6];
    const float* bias_gm    = (const float*)d_in[7];
    const float* kernel_in  = (const float*)d_in[8];
    const float* bias_in    = (const float*)d_in[9];
    const float* mlp_k0     = (const float*)d_in[10];
    const float* mlp_b0     = (const float*)d_in[11];
    const float* mlp_k1     = (const float*)d_in[12];
    const float* mlp_b1     = (const float*)d_in[13];
    float* out = (float*)d_out;

    // ---- workspace carve (bytes) ----
    char* p = (char*)d_ws;
    ushort_t* in_b   = (ushort_t*)p;  p += (size_t)2048 * 1024 * 2;    // 4 MB
    ushort_t* x_b    = (ushort_t*)p;  p += (size_t)2048 * 1024 * 2;    // 4 MB
    ushort_t* wt_in  = (ushort_t*)p;  p += (size_t)1024 * 1024 * 2;    // 2 MB
    ushort_t* wt_qkv = (ushort_t*)p;  p += (size_t)3072 * 1024 * 2;    // 6 MB
    ushort_t* wt_k0  = (ushort_t*)p;  p += (size_t)1024 * 1024 * 2;
    ushort_t* wt_k1  = (ushort_t*)p;  p += (size_t)1024 * 1024 * 2;
    float*    ws_gi  = (float*)p;     p += (size_t)2048 * 2 * 4;
    float*    igfg   = (float*)p;     p += (size_t)16384 * 2 * 4;      // 128 KB
    ushort_t* ws_mpi = (ushort_t*)p;  p += (size_t)18432 * 1024 * 2;   // 36 MB
    ushort_t* m1b    = (ushort_t*)p;  p += (size_t)16384 * 1024 * 2;   // 32 MB
    ushort_t* ws_h   = (ushort_t*)p;  p += (size_t)16384 * 1024 * 2;   // 32 MB
    size_t fixed = (size_t)(p - (char*)d_ws);

    int Bc = 128;   // cap 1024: chunked beats full batch (L2 residency, R3/R4)
    for (int cand = 1024; cand >= 128; cand >>= 1)
        if (fixed + (size_t)cand * 9 * 3072 * 2 <= ws_size) { Bc = cand; break; }
    ushort_t* ws_qkv = (ushort_t*)p;   // Bc*9*3072 bf16

    // ---- conversions ----
    conv_bf16<<<2048, 256, 0, stream>>>(inputs, in_b, (size_t)2048 * 1024);
    dim3 wtb(32, 8);
    conv_wt<<<dim3(32, 32), wtb, 0, stream>>>(kernel_in, wt_in, 1024, 1024);
    conv_wt<<<dim3(96, 32), wtb, 0, stream>>>(kernel_qkv, wt_qkv, 1024, 3072);
    conv_wt<<<dim3(32, 32), wtb, 0, stream>>>(mlp_k0, wt_k0, 1024, 1024);
    conv_wt<<<dim3(32, 32), wtb, 0, stream>>>(mlp_k1, wt_k1, 1024, 1024);

    // x_b = bf16(inputs @ kernel_in + bias_in)   (16 row-tiles x 8 col-tiles)
    gemm_mfma<<<16 * 8, 256, 0, stream>>>(
        in_b, wt_in, bias_in, nullptr, x_b, nullptr, nullptr, nullptr, nullptr,
        1024, 1024, 0, 8, 16);

    gi_kernel<<<2048, 256, 0, stream>>>(x_b, kernel_gi, bias_gi, ws_gi);
    prep_kernel<<<18432, 256, 0, stream>>>(memory, x_b, kernel_gm, bias_gm,
                                           ws_gi, ws_mpi, igfg);

    // qkv + attention, chunked
    const int NC = 2048 / Bc;
    for (int c = 0; c < NC; ++c) {
        const int b0 = c * Bc;
        const int nrow = Bc * 9 / 128;
        gemm_mfma<<<24 * nrow, 256, 0, stream>>>(
            ws_mpi + (size_t)b0 * 9 * 1024, wt_qkv, bias_qkv, nullptr, ws_qkv,
            nullptr, nullptr, nullptr, nullptr, 3072, 1024, 0, 24, nrow);
        attn_kernel<<<Bc * 8, 256, 0, stream>>>(
            ws_qkv, ws_mpi + (size_t)b0 * 9 * 1024, m1b + (size_t)b0 * 8192);
    }

    // h = relu(m1 @ mlp_k0 + mlp_b0), full batch (bf16)
    gemm_mfma<<<128 * 8, 256, 0, stream>>>(
        m1b, wt_k0, mlp_b0, nullptr, ws_h, nullptr, nullptr, nullptr, nullptr,
        1024, 1024, 1, 8, 128);

    // out = ig*tanh(m1 + h @ mlp_k1 + mlp_b1) + fg*mem(bf16 via mpi), fused
    gemm_mfma<<<128 * 8, 256, 0, stream>>>(
        ws_h, wt_k1, mlp_b1, nullptr, nullptr, m1b, igfg, ws_mpi, out,
        1024, 1024, 0, 8, 128);
}